// Round 1
// baseline (281.979 us; speedup 1.0000x reference)
//
#include <hip/hip_runtime.h>

// Problem constants (B,N,D,K) = (32, 2048, 512, 256)
#define CB 32
#define CN 2048
#define CD 512
#define CK 256

typedef __bf16 bf16x8 __attribute__((ext_vector_type(8)));
typedef float  f32x4  __attribute__((ext_vector_type(4)));

__device__ __forceinline__ unsigned short f2bf(float x) {
    union { float f; unsigned u; } a; a.f = x;
    unsigned r = a.u + 0x7fffu + ((a.u >> 16) & 1u);   // RNE
    return (unsigned short)(r >> 16);
}

// ---------------- K0a: vQp[b][k] = vQ[b]·Wq[:,k] + bq[k] ----------------
__global__ __launch_bounds__(256) void vqp_kernel(const float* __restrict__ vQ,
        const float* __restrict__ Wq, const float* __restrict__ bq,
        float* __restrict__ vQp)
{
    const int b = blockIdx.x, tid = threadIdx.x;
    __shared__ float sq[CD];
    sq[tid]       = vQ[b * CD + tid];
    sq[tid + 256] = vQ[b * CD + tid + 256];
    __syncthreads();
    float acc = bq[tid];
    #pragma unroll 8
    for (int d = 0; d < CD; ++d) acc += sq[d] * Wq[d * CK + tid];
    vQp[b * CK + tid] = acc;
}

// ---------------- K0b: WiT[k][d] = bf16(Wi[d][k]) ----------------
__global__ __launch_bounds__(256) void wit_kernel(const float* __restrict__ Wi,
        unsigned short* __restrict__ WiT)
{
    const int k = blockIdx.x, tid = threadIdx.x;
    for (int d = tid; d < CD; d += 256)
        WiT[(size_t)k * CD + d] = f2bf(Wi[(size_t)d * CK + k]);
}

// ---------------- K1: scores[b][n] = sum_k lrelu(vI[n]·Wi[:,k] + vQp[k]) * Wp[k] ----
// BM=64 rows/block, full K=256 cols, BK=64 d-chunk, mfma_f32_16x16x32_bf16.
__global__ __launch_bounds__(256) void scores_kernel(
        const float* __restrict__ vI, const unsigned short* __restrict__ WiT,
        const float* __restrict__ vQp, const float* __restrict__ Wp,
        float* __restrict__ scores)
{
    constexpr int BM = 64, BK = 64, LDP = BK + 8;   // 144B padded rows
    __shared__ __align__(16) unsigned short sA[BM][LDP];
    __shared__ __align__(16) unsigned short sB[CK][LDP];
    __shared__ float sred[4][BM];

    const int tid  = threadIdx.x;
    const int b    = blockIdx.y;
    const int n0   = blockIdx.x * BM;
    const int wave = tid >> 6;
    const int lane = tid & 63;
    const int col  = lane & 15;   // 16-dim index of A-row / B-col / C-col
    const int quad = lane >> 4;   // k-group

    const float* vIb = vI + ((size_t)b * CN + n0) * CD;

    f32x4 acc[4][4];
    #pragma unroll
    for (int mt = 0; mt < 4; ++mt)
        #pragma unroll
        for (int kt = 0; kt < 4; ++kt)
            acc[mt][kt] = (f32x4){0.f, 0.f, 0.f, 0.f};

    const int ar = tid >> 4;         // A stage row 0..15
    const int ac = (tid & 15) * 4;   // A stage col (floats)
    const int bk = tid >> 3;         // B stage row 0..31
    const int bc = (tid & 7) * 8;    // B stage col (ushorts)

    for (int d0 = 0; d0 < CD; d0 += BK) {
        __syncthreads();
        // stage A: 64x64 fp32 -> bf16 LDS
        #pragma unroll
        for (int i = 0; i < 4; ++i) {
            int r = ar + i * 16;
            float4 v = *reinterpret_cast<const float4*>(vIb + (size_t)r * CD + d0 + ac);
            unsigned short* p = &sA[r][ac];
            p[0] = f2bf(v.x); p[1] = f2bf(v.y); p[2] = f2bf(v.z); p[3] = f2bf(v.w);
        }
        // stage B: 256x64 bf16 copy (already k-major)
        #pragma unroll
        for (int i = 0; i < 8; ++i) {
            int k = bk + i * 32;
            uint4 v = *reinterpret_cast<const uint4*>(WiT + (size_t)k * CD + d0 + bc);
            *reinterpret_cast<uint4*>(&sB[k][bc]) = v;
        }
        __syncthreads();
        #pragma unroll
        for (int s = 0; s < 2; ++s) {
            const int dk = s * 32 + quad * 8;
            bf16x8 af[4], bfr[4];
            #pragma unroll
            for (int mt = 0; mt < 4; ++mt)
                af[mt] = *reinterpret_cast<const bf16x8*>(&sA[mt * 16 + col][dk]);
            #pragma unroll
            for (int kt = 0; kt < 4; ++kt)
                bfr[kt] = *reinterpret_cast<const bf16x8*>(&sB[wave * 64 + kt * 16 + col][dk]);
            #pragma unroll
            for (int mt = 0; mt < 4; ++mt)
                #pragma unroll
                for (int kt = 0; kt < 4; ++kt)
                    acc[mt][kt] = __builtin_amdgcn_mfma_f32_16x16x32_bf16(
                        af[mt], bfr[kt], acc[mt][kt], 0, 0, 0);
        }
    }

    // epilogue: per-row score reduction (vIp never leaves registers)
    float vq[4], wp[4];
    #pragma unroll
    for (int kt = 0; kt < 4; ++kt) {
        int k = wave * 64 + kt * 16 + col;
        vq[kt] = vQp[b * CK + k];
        wp[kt] = Wp[k];
    }
    float sp[4][4];
    #pragma unroll
    for (int mt = 0; mt < 4; ++mt)
        #pragma unroll
        for (int r = 0; r < 4; ++r) {
            float s = 0.f;
            #pragma unroll
            for (int kt = 0; kt < 4; ++kt) {
                float v = acc[mt][kt][r] + vq[kt];
                v = v > 0.f ? v : 0.01f * v;     // leaky relu
                s += v * wp[kt];
            }
            sp[mt][r] = s;
        }
    #pragma unroll
    for (int off = 1; off < 16; off <<= 1)
        #pragma unroll
        for (int mt = 0; mt < 4; ++mt)
            #pragma unroll
            for (int r = 0; r < 4; ++r)
                sp[mt][r] += __shfl_xor(sp[mt][r], off);
    if (col == 0) {
        #pragma unroll
        for (int mt = 0; mt < 4; ++mt)
            #pragma unroll
            for (int r = 0; r < 4; ++r)
                sred[wave][mt * 16 + quad * 4 + r] = sp[mt][r];
    }
    __syncthreads();
    if (tid < BM) {
        // bp[0] omitted: softmax-invariant constant shift
        scores[b * CN + n0 + tid] =
            sred[0][tid] + sred[1][tid] + sred[2][tid] + sred[3][tid];
    }
}

// ---------------- K2: per-b softmax -> pi; zero vbar ----------------
__global__ __launch_bounds__(256) void softmax_kernel(const float* __restrict__ scores,
        float* __restrict__ pi, float* __restrict__ vbar)
{
    const int b = blockIdx.x, tid = threadIdx.x;
    const int lane = tid & 63, wave = tid >> 6;
    __shared__ float red[4];
    float s[8];
    float m = -1e30f;
    #pragma unroll
    for (int i = 0; i < 8; ++i) {
        s[i] = scores[b * CN + tid + i * 256];
        m = fmaxf(m, s[i]);
    }
    #pragma unroll
    for (int off = 32; off > 0; off >>= 1) m = fmaxf(m, __shfl_xor(m, off));
    if (lane == 0) red[wave] = m;
    __syncthreads();
    m = fmaxf(fmaxf(red[0], red[1]), fmaxf(red[2], red[3]));
    float z = 0.f;
    #pragma unroll
    for (int i = 0; i < 8; ++i) { s[i] = __expf(s[i] - m); z += s[i]; }
    #pragma unroll
    for (int off = 32; off > 0; off >>= 1) z += __shfl_xor(z, off);
    __syncthreads();
    if (lane == 0) red[wave] = z;
    __syncthreads();
    z = red[0] + red[1] + red[2] + red[3];
    float inv = 1.f / z;
    #pragma unroll
    for (int i = 0; i < 8; ++i) pi[b * CN + tid + i * 256] = s[i] * inv;
    vbar[b * CD + tid] = 0.f;
    vbar[b * CD + tid + 256] = 0.f;
}

// ---------------- K3: vbar[b][d] = sum_n pi[b][n] * vI[b][n][d] (fp32 exact) ----
__global__ __launch_bounds__(256) void vbar_kernel(const float* __restrict__ vI,
        const float* __restrict__ pi, float* __restrict__ vbar)
{
    constexpr int RN = 128;
    const int b = blockIdx.y, n0 = blockIdx.x * RN, tid = threadIdx.x;
    __shared__ float sp[RN];
    if (tid < RN) sp[tid] = pi[b * CN + n0 + tid];
    __syncthreads();
    const float* base = vI + ((size_t)b * CN + n0) * CD;
    float a0 = 0.f, a1 = 0.f;
    #pragma unroll 4
    for (int nn = 0; nn < RN; ++nn) {
        float p = sp[nn];
        const float* r = base + (size_t)nn * CD;
        a0 += p * r[tid];
        a1 += p * r[tid + 256];
    }
    atomicAdd(&vbar[b * CD + tid], a0);
    atomicAdd(&vbar[b * CD + tid + 256], a1);
}

// ---------------- K4: out[b][k] = vbar[b]·Wi[:,k] + vQp[b][k] ----------------
__global__ __launch_bounds__(256) void out_kernel(const float* __restrict__ vbar,
        const float* __restrict__ Wi, const float* __restrict__ vQp,
        float* __restrict__ out)
{
    const int b = blockIdx.x, tid = threadIdx.x;
    __shared__ float sv[CD];
    sv[tid]       = vbar[b * CD + tid];
    sv[tid + 256] = vbar[b * CD + tid + 256];
    __syncthreads();
    float acc = vQp[b * CK + tid];
    #pragma unroll 8
    for (int d = 0; d < CD; ++d) acc += sv[d] * Wi[d * CK + tid];
    out[b * CK + tid] = acc;
}

extern "C" void kernel_launch(void* const* d_in, const int* in_sizes, int n_in,
                              void* d_out, int out_size, void* d_ws, size_t ws_size,
                              hipStream_t stream)
{
    const float* vI = (const float*)d_in[0];   // [B,N,D]
    const float* vQ = (const float*)d_in[1];   // [B,D]
    const float* Wi = (const float*)d_in[2];   // [D,K]
    const float* Wq = (const float*)d_in[3];   // [D,K]
    const float* bq = (const float*)d_in[4];   // [K]
    const float* Wp = (const float*)d_in[5];   // [K,1]
    // d_in[6] = bp: softmax-invariant, unused
    float* out = (float*)d_out;                // [B,K]

    char* ws = (char*)d_ws;
    float* vQp    = (float*)(ws);                                  //  32 KB
    float* scores = (float*)(ws + 32768);                          // 256 KB
    float* pi     = (float*)(ws + 32768 + 262144);                 // 256 KB
    float* vbar   = (float*)(ws + 32768 + 2 * 262144);             //  64 KB
    unsigned short* WiT = (unsigned short*)(ws + 32768 + 2 * 262144 + 65536); // 256 KB

    vqp_kernel    <<<CB, 256, 0, stream>>>(vQ, Wq, bq, vQp);
    wit_kernel    <<<CK, 256, 0, stream>>>(Wi, WiT);
    scores_kernel <<<dim3(CN / 64, CB), 256, 0, stream>>>(vI, WiT, vQp, Wp, scores);
    softmax_kernel<<<CB, 256, 0, stream>>>(scores, pi, vbar);
    vbar_kernel   <<<dim3(CN / 128, CB), 256, 0, stream>>>(vI, pi, vbar);
    out_kernel    <<<CB, 256, 0, stream>>>(vbar, Wi, vQp, out);
}

// Round 2
// 274.776 us; speedup vs baseline: 1.0262x; 1.0262x over previous
//
#include <hip/hip_runtime.h>

// (B,N,D,K) = (32, 2048, 512, 256)
#define CB 32
#define CN 2048
#define CD 512
#define CK 256

typedef __bf16 bf16x8 __attribute__((ext_vector_type(8)));
typedef float  f32x4  __attribute__((ext_vector_type(4)));

__device__ __forceinline__ unsigned pk2bf(float a, float b) {   // RNE pack: 2 f32 -> bf16x2
    union { float f; unsigned u; } x, y; x.f = a; y.f = b;
    unsigned ru = x.u + 0x7fffu + ((x.u >> 16) & 1u);
    unsigned rv = y.u + 0x7fffu + ((y.u >> 16) & 1u);
    return (ru >> 16) | (rv & 0xffff0000u);
}

__device__ __forceinline__ void glds16(const void* g, void* l) {
    __builtin_amdgcn_global_load_lds(
        (const __attribute__((address_space(1))) void*)g,
        (__attribute__((address_space(3))) void*)l, 16, 0, 0);
}

// ---------------- K0a: vQp[b][k] = vQ[b]·Wq[:,k] + bq[k] ----------------
__global__ __launch_bounds__(256) void vqp_kernel(const float* __restrict__ vQ,
        const float* __restrict__ Wq, const float* __restrict__ bq,
        float* __restrict__ vQp)
{
    const int b = blockIdx.x, tid = threadIdx.x;
    __shared__ float sq[CD];
    sq[tid]       = vQ[b * CD + tid];
    sq[tid + 256] = vQ[b * CD + tid + 256];
    __syncthreads();
    float acc = bq[tid];
    #pragma unroll 8
    for (int d = 0; d < CD; ++d) acc += sq[d] * Wq[d * CK + tid];
    vQp[b * CK + tid] = acc;
}

// ---------------- K0b: WiT[k][d] = bf16(Wi[d][k]) (k-major, linear) ----------------
__global__ __launch_bounds__(256) void wit_kernel(const float* __restrict__ Wi,
        unsigned short* __restrict__ WiT)
{
    const int k = blockIdx.x, tid = threadIdx.x;
    for (int d = tid; d < CD; d += 256) {
        union { float f; unsigned u; } x; x.f = Wi[(size_t)d * CK + k];
        unsigned r = x.u + 0x7fffu + ((x.u >> 16) & 1u);
        WiT[(size_t)k * CD + d] = (unsigned short)(r >> 16);
    }
}

// ---------------- K1: fused scores + online-softmax partial num/Z/m ----------------
// BM=128 rows/block, all K=256 cols, BK=64. grid (16, 32).
__global__ __launch_bounds__(256, 2) void scores_fused_kernel(
        const float* __restrict__ vI, const unsigned short* __restrict__ WiT,
        const float* __restrict__ vQp, const float* __restrict__ Wp,
        float* __restrict__ numP, float* __restrict__ Zp, float* __restrict__ mP)
{
    constexpr int BM = 128, BK = 64, LDA = BK + 8;          // A rows padded: 144 B
    __shared__ __align__(16) unsigned short sA[BM][LDA];    // 18 KB
    __shared__ __align__(16) unsigned short sB[CK * BK];    // 32 KB, swizzled; aliased post-loop
    float* sred = (float*)sB;          // [4][128]
    float* sS   = ((float*)sB) + 512;  // [128] scores (later [0..3] reused for Z partials)
    float* sW   = ((float*)sB) + 640;  // [128] exp weights
    float* sacc = ((float*)sB) + 1024; // [4][512] num partials

    const int tid  = threadIdx.x;
    const int b    = blockIdx.y;
    const int n0   = blockIdx.x * BM;
    const int wave = tid >> 6;
    const int lane = tid & 63;
    const int col  = lane & 15;
    const int quad = lane >> 4;

    const float* vIb = vI + ((size_t)b * CN + n0) * CD;

    // B glds source offsets (swizzled chunk): instr t covers rows wave*64+t*8 .. +8
    int gBoff[8];
    #pragma unroll
    for (int t = 0; t < 8; ++t) {
        int row = wave * 64 + t * 8 + (lane >> 3);
        int c   = (lane & 7) ^ (row & 7);
        gBoff[t] = row * CD + c * 8;    // ushort index; +d0 per chunk
    }

    f32x4 acc[8][4];
    #pragma unroll
    for (int mt = 0; mt < 8; ++mt)
        #pragma unroll
        for (int kt = 0; kt < 4; ++kt)
            acc[mt][kt] = (f32x4){0.f, 0.f, 0.f, 0.f};

    const int ar = tid >> 4;         // A stage row 0..15 (+i*16)
    const int ac = (tid & 15) * 4;   // A stage col (floats)

    for (int d0 = 0; d0 < CD; d0 += BK) {
        __syncthreads();
        // B: async global->LDS, 8 instr/wave, lane-linear LDS, swizzled source
        #pragma unroll
        for (int t = 0; t < 8; ++t)
            glds16(WiT + gBoff[t] + d0, (unsigned short*)sB + (wave * 8 + t) * 512);
        // A: fp32 -> bf16 -> LDS (padded rows)
        #pragma unroll
        for (int i = 0; i < 8; ++i) {
            int r = ar + i * 16;
            float4 v = *reinterpret_cast<const float4*>(vIb + (size_t)r * CD + d0 + ac);
            uint2 p; p.x = pk2bf(v.x, v.y); p.y = pk2bf(v.z, v.w);
            *reinterpret_cast<uint2*>(&sA[r][ac]) = p;
        }
        __syncthreads();
        #pragma unroll
        for (int s = 0; s < 2; ++s) {
            const int dk = s * 32 + quad * 8;
            const int slot = (4 * s + quad) ^ (col & 7);
            bf16x8 af[8], bfr[4];
            #pragma unroll
            for (int mt = 0; mt < 8; ++mt)
                af[mt] = *reinterpret_cast<const bf16x8*>(&sA[mt * 16 + col][dk]);
            #pragma unroll
            for (int kt = 0; kt < 4; ++kt) {
                int R = wave * 64 + kt * 16 + col;
                bfr[kt] = *reinterpret_cast<const bf16x8*>(
                    (unsigned short*)sB + R * 64 + slot * 8);
            }
            #pragma unroll
            for (int mt = 0; mt < 8; ++mt)
                #pragma unroll
                for (int kt = 0; kt < 4; ++kt)
                    acc[mt][kt] = __builtin_amdgcn_mfma_f32_16x16x32_bf16(
                        af[mt], bfr[kt], acc[mt][kt], 0, 0, 0);
        }
    }

    // ---- epilogue 1: per-row scores (vIp never materialized) ----
    float vq[4], wp[4];
    #pragma unroll
    for (int kt = 0; kt < 4; ++kt) {
        int k = wave * 64 + kt * 16 + col;
        vq[kt] = vQp[b * CK + k];
        wp[kt] = Wp[k];
    }
    float sp[8][4];
    #pragma unroll
    for (int mt = 0; mt < 8; ++mt)
        #pragma unroll
        for (int r = 0; r < 4; ++r) {
            float s = 0.f;
            #pragma unroll
            for (int kt = 0; kt < 4; ++kt) {
                float v = acc[mt][kt][r] + vq[kt];
                v = v > 0.f ? v : 0.01f * v;
                s += v * wp[kt];
            }
            sp[mt][r] = s;
        }
    #pragma unroll
    for (int off = 1; off < 16; off <<= 1)
        #pragma unroll
        for (int mt = 0; mt < 8; ++mt)
            #pragma unroll
            for (int r = 0; r < 4; ++r)
                sp[mt][r] += __shfl_xor(sp[mt][r], off);

    __syncthreads();   // all sB ds_reads done; safe to alias
    if (col == 0) {
        #pragma unroll
        for (int mt = 0; mt < 8; ++mt)
            #pragma unroll
            for (int r = 0; r < 4; ++r)
                sred[wave * 128 + mt * 16 + quad * 4 + r] = sp[mt][r];
    }
    __syncthreads();
    if (tid < BM)
        sS[tid] = sred[tid] + sred[128 + tid] + sred[256 + tid] + sred[384 + tid];
    __syncthreads();

    // ---- epilogue 2: block-local softmax pieces ----
    float m = -1e30f;
    #pragma unroll 8
    for (int i = 0; i < BM; ++i) m = fmaxf(m, sS[i]);
    if (tid < BM) sW[tid] = __expf(sS[tid] - m);
    __syncthreads();
    float z = (tid < BM) ? sW[tid] : 0.f;
    #pragma unroll
    for (int off = 32; off > 0; off >>= 1) z += __shfl_xor(z, off);
    if (lane == 0) sS[wave] = z;     // sS scores no longer needed
    __syncthreads();
    const int pidx = b * 16 + blockIdx.x;
    if (tid == 0) {
        Zp[pidx] = sS[0] + sS[1] + sS[2] + sS[3];
        mP[pidx] = m;
    }

    // ---- epilogue 3: num = sum_n w_n * vI_n (fp32, L2-hot re-read) ----
    float a8[8] = {0.f, 0.f, 0.f, 0.f, 0.f, 0.f, 0.f, 0.f};
    const float* vrow = vIb + (size_t)(wave * 32) * CD + lane * 8;
    #pragma unroll 4
    for (int i = 0; i < 32; ++i) {
        float w = sW[wave * 32 + i];
        float4 u0 = *reinterpret_cast<const float4*>(vrow);
        float4 u1 = *reinterpret_cast<const float4*>(vrow + 4);
        a8[0] += w * u0.x; a8[1] += w * u0.y; a8[2] += w * u0.z; a8[3] += w * u0.w;
        a8[4] += w * u1.x; a8[5] += w * u1.y; a8[6] += w * u1.z; a8[7] += w * u1.w;
        vrow += CD;
    }
    #pragma unroll
    for (int j = 0; j < 8; ++j) sacc[wave * 512 + lane * 8 + j] = a8[j];
    __syncthreads();
    for (int c = tid; c < CD; c += 256) {
        numP[(size_t)pidx * CD + c] =
            sacc[c] + sacc[512 + c] + sacc[1024 + c] + sacc[1536 + c];
    }
}

// ---------------- K2: combine partials -> vbar; out = vbar@Wi + vQp ----------------
__global__ __launch_bounds__(256) void finalize_kernel(
        const float* __restrict__ numP, const float* __restrict__ Zp,
        const float* __restrict__ mP, const float* __restrict__ Wi,
        const float* __restrict__ vQp, float* __restrict__ out)
{
    const int b = blockIdx.x, tid = threadIdx.x;
    __shared__ float sv[CD];
    float M = -1e30f;
    #pragma unroll
    for (int j = 0; j < 16; ++j) M = fmaxf(M, mP[b * 16 + j]);
    float w[16]; float Zt = 0.f;
    #pragma unroll
    for (int j = 0; j < 16; ++j) {
        w[j] = __expf(mP[b * 16 + j] - M);
        Zt += w[j] * Zp[b * 16 + j];
    }
    const float inv = 1.f / Zt;
    for (int c = tid; c < CD; c += 256) {
        float s = 0.f;
        #pragma unroll
        for (int j = 0; j < 16; ++j) s += w[j] * numP[(size_t)(b * 16 + j) * CD + c];
        sv[c] = s * inv;
    }
    __syncthreads();
    float acc = vQp[b * CK + tid];
    #pragma unroll 8
    for (int d = 0; d < CD; ++d) acc += sv[d] * Wi[d * CK + tid];
    out[b * CK + tid] = acc;
}

extern "C" void kernel_launch(void* const* d_in, const int* in_sizes, int n_in,
                              void* d_out, int out_size, void* d_ws, size_t ws_size,
                              hipStream_t stream)
{
    const float* vI = (const float*)d_in[0];   // [B,N,D]
    const float* vQ = (const float*)d_in[1];   // [B,D]
    const float* Wi = (const float*)d_in[2];   // [D,K]
    const float* Wq = (const float*)d_in[3];   // [D,K]
    const float* bq = (const float*)d_in[4];   // [K]
    const float* Wp = (const float*)d_in[5];   // [K,1]
    // d_in[6] = bp: softmax-invariant, unused
    float* out = (float*)d_out;                // [B,K]

    char* ws = (char*)d_ws;
    float*          vQp  = (float*)(ws);                       //  32 KB
    unsigned short* WiT  = (unsigned short*)(ws + 32768);      // 256 KB
    float*          numP = (float*)(ws + 32768 + 262144);      //   1 MB
    float*          Zp   = (float*)(ws + 32768 + 262144 + 1048576);
    float*          mP   = (float*)(ws + 32768 + 262144 + 1048576 + 2048);

    vqp_kernel         <<<CB, 256, 0, stream>>>(vQ, Wq, bq, vQp);
    wit_kernel         <<<CK, 256, 0, stream>>>(Wi, WiT);
    scores_fused_kernel<<<dim3(CN / 128, CB), 256, 0, stream>>>(vI, WiT, vQp, Wp,
                                                                numP, Zp, mP);
    finalize_kernel    <<<CB, 256, 0, stream>>>(numP, Zp, mP, Wi, vQp, out);
}